// Round 10
// baseline (200.662 us; speedup 1.0000x reference)
//
#include <hip/hip_runtime.h>
#include <hip/hip_bf16.h>

#define N_NODES 100000
#define N_EDGES 3200000
#define F_IN 36
#define F_HID 8
#define F_OUT 2
#define NEG_SLOPE 0.2f

// parent buckets (partition granularity)
#define SHIFT 8
#define NPB 256
#define NBUCK 391
#define NB_PART 256
#define CHUNK 12500
#define NS (NBUCK * NB_PART)
#define BP 1024

// child buckets (gatF1 granularity)
#define GSHIFT 7
#define GNPB 128
#define GNBUCK 782
#define BPG 512
#define ECAP 4608

__device__ __forceinline__ int detect_is64(const void* eidx, int* s_flag) {
    if (threadIdx.x < 64) {
        const unsigned int* p = (const unsigned int*)eidx;
        unsigned int v1 = p[2 * threadIdx.x + 1];
        unsigned int v2 = p[2 * (threadIdx.x + 64) + 1];
        unsigned long long m = __ballot(v1 != 0u || v2 != 0u);
        if (threadIdx.x == 0) *s_flag = (m == 0ull) ? 1 : 0;
    }
    __syncthreads();
    return *s_flag;
}

__global__ void count_k(const void* __restrict__ eidx, int* __restrict__ blk_cnt) {
    __shared__ int h[NBUCK];
    __shared__ int s_flag;
    int t = threadIdx.x;
    for (int i = t; i < NBUCK; i += BP) h[i] = 0;
    int f = detect_is64(eidx, &s_flag);
    __syncthreads();
    int beg = blockIdx.x * CHUNK;
    int end = beg + CHUNK; if (end > N_EDGES) end = N_EDGES;
    if (f) {
        const long long* p = (const long long*)eidx;
        for (int i = beg + t; i < end; i += BP) atomicAdd(&h[(int)p[N_EDGES + i] >> SHIFT], 1);
    } else {
        const int* p = (const int*)eidx;
        for (int i = beg + t; i < end; i += BP) atomicAdd(&h[p[N_EDGES + i] >> SHIFT], 1);
    }
    __syncthreads();
    for (int i = t; i < NBUCK; i += BP) blk_cnt[i * NB_PART + blockIdx.x] = h[i];
}

__global__ void scanA_k(int* __restrict__ blk_cnt, int* __restrict__ tot) {
    __shared__ int s[NB_PART];
    int t = threadIdx.x;
    int idx = blockIdx.x * NB_PART + t;
    int v = blk_cnt[idx];
    s[t] = v;
    __syncthreads();
    for (int o = 1; o < NB_PART; o <<= 1) {
        int u = (t >= o) ? s[t - o] : 0;
        __syncthreads();
        s[t] += u;
        __syncthreads();
    }
    blk_cnt[idx] = s[t] - v;
    if (t == NB_PART - 1) tot[blockIdx.x] = s[t];
}

__global__ void scanB_k(const int* __restrict__ tot, int* __restrict__ base) {
    __shared__ int s[512];
    int t = threadIdx.x;
    int orig = (t < NBUCK) ? tot[t] : 0;
    s[t] = orig;
    __syncthreads();
    for (int o = 1; o < 512; o <<= 1) {
        int u = (t >= o) ? s[t - o] : 0;
        __syncthreads();
        s[t] += u;
        __syncthreads();
    }
    if (t < NBUCK) base[t] = s[t] - orig;
    if (t == NBUCK - 1) base[NBUCK] = s[t];
}

__global__ void partition_k(const void* __restrict__ eidx, const int* __restrict__ blk_cnt,
                            const int* __restrict__ base, int* __restrict__ partP) {
    __shared__ int cur[NBUCK];
    __shared__ int s_flag;
    int t = threadIdx.x;
    int f = detect_is64(eidx, &s_flag);
    for (int i = t; i < NBUCK; i += BP)
        cur[i] = base[i] + blk_cnt[i * NB_PART + blockIdx.x];
    __syncthreads();
    int beg = blockIdx.x * CHUNK;
    int end = beg + CHUNK; if (end > N_EDGES) end = N_EDGES;
    if (f) {
        const long long* p = (const long long*)eidx;
        for (int i = beg + t; i < end; i += BP) {
            int s = (int)p[i];
            int d = (int)p[N_EDGES + i];
            int pos = atomicAdd(&cur[d >> SHIFT], 1);
            partP[pos] = (s << SHIFT) | (d & (NPB - 1));
        }
    } else {
        const int* p = (const int*)eidx;
        for (int i = beg + t; i < end; i += BP) {
            int s = p[i];
            int d = p[N_EDGES + i];
            int pos = atomicAdd(&cur[d >> SHIFT], 1);
            partP[pos] = (s << SHIFT) | (d & (NPB - 1));
        }
    }
}

__global__ void node1_k(const float* __restrict__ x, const float* __restrict__ W1,
                        const float* __restrict__ aw_s, const float* __restrict__ aw_d,
                        float* __restrict__ h1, float* __restrict__ as1, float* __restrict__ ad1,
                        int n_nodes) {
    int n = blockIdx.x * blockDim.x + threadIdx.x;
    if (n >= n_nodes) return;
    float acc[F_HID];
#pragma unroll
    for (int f = 0; f < F_HID; f++) acc[f] = 0.f;
    const float* xp = x + (size_t)n * F_IN;
#pragma unroll
    for (int k = 0; k < F_IN; k++) {
        float xv = xp[k];
#pragma unroll
        for (int f = 0; f < F_HID; f++) acc[f] += xv * W1[k * F_HID + f];
    }
    float s = 0.f, d = 0.f;
#pragma unroll
    for (int f = 0; f < F_HID; f++) {
        s += acc[f] * aw_s[f];
        d += acc[f] * aw_d[f];
        h1[(size_t)n * F_HID + f] = acc[f];
    }
    as1[n] = s;
    ad1[n] = d;
}

// one block per CHILD (128 nodes); scans parent range, keeps own half.
__global__ void gatF1_k(const int* __restrict__ base, const int* __restrict__ partP,
                        int* __restrict__ e_src, int* __restrict__ row_ptr,
                        const float* __restrict__ as1, const float* __restrict__ ad1,
                        const float* __restrict__ h1, const float* __restrict__ b1,
                        const float* __restrict__ W2, const float* __restrict__ aw_s2,
                        const float* __restrict__ aw_d2, float* __restrict__ h2,
                        float* __restrict__ as2, float* __restrict__ ad2) {
    __shared__ int eL[ECAP];
    __shared__ int hist[GNPB];
    __shared__ int nstart[GNPB];
    __shared__ int cursor[GNPB];
    __shared__ int sscan[GNPB];
    __shared__ float adl[GNPB];
    __shared__ int s_sum0;
    int t = threadIdx.x;
    int c = blockIdx.x;
    int p = c >> 1;
    int half = c & 1;
    int nbase = c << GSHIFT;
    int pbeg = base[p], pend = base[p + 1];

    if (t == 0) s_sum0 = 0;
    if (t < GNPB) {
        hist[t] = 0;
        adl[t] = (nbase + t < N_NODES) ? ad1[nbase + t] : 0.f;
    }
    __syncthreads();
    // pass 1: histogram own half; ballot-count sibling(bit7==0) edges
    int niter = (pend - pbeg + BPG - 1) / BPG;
    for (int it = 0; it < niter; it++) {
        int j = pbeg + it * BPG + t;
        bool inr = j < pend;
        int pk = inr ? partP[j] : 0;
        int hb = (pk >> GSHIFT) & 1;
        unsigned long long mb = __ballot(inr && hb == 0);
        if ((t & 63) == 0) atomicAdd(&s_sum0, (int)__popcll(mb));
        if (inr && hb == half) atomicAdd(&hist[pk & (GNPB - 1)], 1);
    }
    __syncthreads();
    if (t < GNPB) sscan[t] = hist[t];
    __syncthreads();
    for (int o = 1; o < GNPB; o <<= 1) {
        int u = (t < GNPB && t >= o) ? sscan[t - o] : 0;
        __syncthreads();
        if (t < GNPB) sscan[t] += u;
        __syncthreads();
    }
    int cbeg = pbeg + (half ? s_sum0 : 0);
    if (t < GNPB) {
        int ex = sscan[t] - hist[t];
        nstart[t] = ex;
        cursor[t] = ex;
        int node = nbase + t;
        if (node < N_NODES) row_ptr[node] = cbeg + ex;
    }
    if (c == GNBUCK - 1 && t == 0) row_ptr[N_NODES] = N_EDGES;
    __syncthreads();
    // pass 2: scatter own-half src into LDS sorted by local dst
    for (int j = pbeg + t; j < pend; j += BPG) {
        int pk = partP[j];
        if (((pk >> GSHIFT) & 1) == half) {
            int pos = atomicAdd(&cursor[pk & (GNPB - 1)], 1);
            if (pos < ECAP) eL[pos] = pk >> SHIFT;
        }
    }
    __syncthreads();
    int cnt = sscan[GNPB - 1];
    int cap = cnt < ECAP ? cnt : ECAP;
    for (int i = t; i < cap; i += BPG) e_src[cbeg + i] = eL[i];

    int node = t >> 2;
    int lane = t & 3;
    int gnode = nbase + node;
    if (gnode >= N_NODES) return;
    int ns = nstart[node];
    int ne = ns + hist[node];
    if (ne > ECAP) ne = ECAP;
    float add = adl[node];

    float denom = 0.f;
    float acc[F_HID];
#pragma unroll
    for (int f = 0; f < F_HID; f++) acc[f] = 0.f;
    for (int i = ns + lane; i < ne; i += 4) {
        int s = eL[i];
        float e = as1[s] + add;
        e = e >= 0.f ? e : NEG_SLOPE * e;
        float ee = __expf(e);
        denom += ee;
        const float4* hp = (const float4*)(h1 + (size_t)s * F_HID);
        float4 p0 = hp[0], p1 = hp[1];
        acc[0] += ee * p0.x; acc[1] += ee * p0.y; acc[2] += ee * p0.z; acc[3] += ee * p0.w;
        acc[4] += ee * p1.x; acc[5] += ee * p1.y; acc[6] += ee * p1.z; acc[7] += ee * p1.w;
    }
#pragma unroll
    for (int o = 2; o > 0; o >>= 1) {
        denom += __shfl_xor(denom, o, 4);
#pragma unroll
        for (int f = 0; f < F_HID; f++) acc[f] += __shfl_xor(acc[f], o, 4);
    }
    if (lane == 0) {
        float inv = denom > 0.f ? 1.f / denom : 0.f;
        float o0 = 0.f, o1 = 0.f;
#pragma unroll
        for (int f = 0; f < F_HID; f++) {
            float v = acc[f] * inv + b1[f];
            v = v > 0.f ? v : 0.f;
            o0 += v * W2[f * F_OUT + 0];
            o1 += v * W2[f * F_OUT + 1];
        }
        ((float2*)h2)[gnode] = make_float2(o0, o1);
        as2[gnode] = o0 * aw_s2[0] + o1 * aw_s2[1];
        ad2[gnode] = o0 * aw_d2[0] + o1 * aw_d2[1];
    }
}

__global__ void gat2_k(const int* __restrict__ row_ptr, const int* __restrict__ e_src,
                       const float* __restrict__ as2, const float* __restrict__ ad2,
                       const float* __restrict__ h2, const float* __restrict__ b2,
                       float* __restrict__ out, int n_nodes) {
    int gid = blockIdx.x * 16 + (threadIdx.x >> 4);
    int lane = threadIdx.x & 15;
    if (gid >= n_nodes) return;
    int beg = row_ptr[gid], end = row_ptr[gid + 1];
    float add = ad2[gid];

    float denom = 0.f, a0 = 0.f, a1 = 0.f;
    for (int j = beg + lane; j < end; j += 16) {
        int s = e_src[j];
        float e = as2[s] + add;
        e = e >= 0.f ? e : NEG_SLOPE * e;
        float ee = __expf(e);
        denom += ee;
        float2 p = ((const float2*)h2)[s];
        a0 += ee * p.x;
        a1 += ee * p.y;
    }
#pragma unroll
    for (int o = 8; o > 0; o >>= 1) {
        denom += __shfl_xor(denom, o, 16);
        a0 += __shfl_xor(a0, o, 16);
        a1 += __shfl_xor(a1, o, 16);
    }

    if (lane == 0) {
        float inv = denom > 0.f ? 1.f / denom : 0.f;
        float o0 = a0 * inv + b2[0];
        float o1 = a1 * inv + b2[1];
        float M = fmaxf(o0, o1);
        float l = M + logf(__expf(o0 - M) + __expf(o1 - M));
        ((float2*)out)[gid] = make_float2(o0 - l, o1 - l);
    }
}

extern "C" void kernel_launch(void* const* d_in, const int* in_sizes, int n_in,
                              void* d_out, int out_size, void* d_ws, size_t ws_size,
                              hipStream_t stream) {
    const float* x      = (const float*)d_in[0];
    const void*  eidx   = d_in[1];
    const float* W1     = (const float*)d_in[2];
    const float* a_src1 = (const float*)d_in[3];
    const float* a_dst1 = (const float*)d_in[4];
    const float* b1     = (const float*)d_in[5];
    const float* W2     = (const float*)d_in[6];
    const float* a_src2 = (const float*)d_in[7];
    const float* a_dst2 = (const float*)d_in[8];
    const float* b2     = (const float*)d_in[9];
    float* out = (float*)d_out;

    const size_t N = N_NODES, E = N_EDGES;

    int* wsi = (int*)d_ws;
    float* wsf = (float*)d_ws;
    size_t o = 0;
    int* partP   = wsi + o;     o += E;
    int* e_src   = wsi + o;     o += E;
    int* blk_cnt = wsi + o;     o += NS;
    int* tot     = wsi + o;     o += 448;
    int* base    = wsi + o;     o += 400;
    int* row_ptr = wsi + o;     o += N + 64;
    float* as1   = wsf + o;     o += N;
    float* ad1   = wsf + o;     o += N;
    float* h1    = wsf + o;     o += 8 * N;
    float* h2    = wsf + o;     o += 2 * N;
    float* as2   = wsf + o;     o += N;
    float* ad2   = wsf + o;     o += N;

    const int B = 256;
    const int gridN = (int)((N + B - 1) / B);
    const int gridG = (int)(N / 16);

    count_k<<<NB_PART, BP, 0, stream>>>(eidx, blk_cnt);
    scanA_k<<<NBUCK, NB_PART, 0, stream>>>(blk_cnt, tot);
    scanB_k<<<1, 512, 0, stream>>>(tot, base);
    partition_k<<<NB_PART, BP, 0, stream>>>(eidx, blk_cnt, base, partP);

    node1_k<<<gridN, B, 0, stream>>>(x, W1, a_src1, a_dst1, h1, as1, ad1, (int)N);
    gatF1_k<<<GNBUCK, BPG, 0, stream>>>(base, partP, e_src, row_ptr, as1, ad1, h1, b1,
                                        W2, a_src2, a_dst2, h2, as2, ad2);
    gat2_k<<<gridG, B, 0, stream>>>(row_ptr, e_src, as2, ad2, h2, b2, out, (int)N);
}

// Round 11
// 185.022 us; speedup vs baseline: 1.0845x; 1.0845x over previous
//
#include <hip/hip_runtime.h>
#include <hip/hip_bf16.h>

#define N_NODES 100000
#define N_EDGES 3200000
#define F_IN 36
#define F_HID 8
#define F_OUT 2
#define NEG_SLOPE 0.2f

// bucket parameters: 128 nodes per bucket, padded regions of CAP edges
#define GSHIFT 7
#define GNPB 128                     // nodes per bucket
#define GNBUCK 782                   // ceil(N_NODES / GNPB)
#define CAP 4608                     // per-bucket capacity (mean 4092, +8 sigma)
#define NB_PART 256                  // blocks in partition kernel
#define CHUNK 12500                  // ceil(N_EDGES / NB_PART)
#define BP 1024                      // partition block size
#define BPG 512                      // gatF1 block size (8 waves)

// ---------- inline index-dtype detection (wave 0, 2 loads/lane + ballot) ----------
// int64 input => odd 32-bit words of first 128 index pairs are all zero.
__device__ __forceinline__ int detect_is64(const void* eidx, int* s_flag) {
    if (threadIdx.x < 64) {
        const unsigned int* p = (const unsigned int*)eidx;
        unsigned int v1 = p[2 * threadIdx.x + 1];
        unsigned int v2 = p[2 * (threadIdx.x + 64) + 1];
        unsigned long long m = __ballot(v1 != 0u || v2 != 0u);
        if (threadIdx.x == 0) *s_flag = (m == 0ull) ? 1 : 0;
    }
    __syncthreads();
    return *s_flag;
}

// ---------- fused count+partition: padded per-bucket regions, global atomic bases ----------
// Pass 1: LDS histogram of own chunk. Reserve: one global atomicAdd per (block,bucket).
// Pass 2: scatter packed (src<<7)|(dst&127) into partP[bucket*CAP + pos] (chunk is L2-warm).
__global__ void partition1_k(const void* __restrict__ eidx, int* __restrict__ gcnt,
                             int* __restrict__ partP) {
    __shared__ int h[GNBUCK];
    __shared__ int s_flag;
    int t = threadIdx.x;
    for (int i = t; i < GNBUCK; i += BP) h[i] = 0;
    int f = detect_is64(eidx, &s_flag);   // ends with __syncthreads()
    int beg = blockIdx.x * CHUNK;
    int end = beg + CHUNK; if (end > N_EDGES) end = N_EDGES;
    if (f) {
        const long long* p = (const long long*)eidx;
        for (int i = beg + t; i < end; i += BP) atomicAdd(&h[(int)p[N_EDGES + i] >> GSHIFT], 1);
    } else {
        const int* p = (const int*)eidx;
        for (int i = beg + t; i < end; i += BP) atomicAdd(&h[p[N_EDGES + i] >> GSHIFT], 1);
    }
    __syncthreads();
    // convert counts to absolute cursors via global reservation
    for (int i = t; i < GNBUCK; i += BP) {
        int c = h[i];
        h[i] = c ? atomicAdd(&gcnt[i], c) : 0;
    }
    __syncthreads();
    if (f) {
        const long long* p = (const long long*)eidx;
        for (int i = beg + t; i < end; i += BP) {
            int s = (int)p[i];
            int d = (int)p[N_EDGES + i];
            int b = d >> GSHIFT;
            int pos = atomicAdd(&h[b], 1);
            if (pos < CAP) partP[b * CAP + pos] = (s << GSHIFT) | (d & (GNPB - 1));
        }
    } else {
        const int* p = (const int*)eidx;
        for (int i = beg + t; i < end; i += BP) {
            int s = p[i];
            int d = p[N_EDGES + i];
            int b = d >> GSHIFT;
            int pos = atomicAdd(&h[b], 1);
            if (pos < CAP) partP[b * CAP + pos] = (s << GSHIFT) | (d & (GNPB - 1));
        }
    }
}

// ---------- layer 1 node transform: h1 = x @ W1, alpha_s/alpha_d (float4 I/O) ----------
__global__ void node1_k(const float* __restrict__ x, const float* __restrict__ W1,
                        const float* __restrict__ aw_s, const float* __restrict__ aw_d,
                        float* __restrict__ h1, float* __restrict__ as1, float* __restrict__ ad1,
                        int n_nodes) {
    int n = blockIdx.x * blockDim.x + threadIdx.x;
    if (n >= n_nodes) return;
    float acc[F_HID];
#pragma unroll
    for (int f = 0; f < F_HID; f++) acc[f] = 0.f;
    const float4* xp = (const float4*)(x + (size_t)n * F_IN);  // 36 floats = 9 float4, 144B rows stay 16B-aligned
#pragma unroll
    for (int q = 0; q < 9; q++) {
        float4 xv = xp[q];
        const float* w = W1 + q * 4 * F_HID;
#pragma unroll
        for (int f = 0; f < F_HID; f++) {
            acc[f] += xv.x * w[0 * F_HID + f] + xv.y * w[1 * F_HID + f]
                    + xv.z * w[2 * F_HID + f] + xv.w * w[3 * F_HID + f];
        }
    }
    float s = 0.f, d = 0.f;
#pragma unroll
    for (int f = 0; f < F_HID; f++) {
        s += acc[f] * aw_s[f];
        d += acc[f] * aw_d[f];
    }
    float4* hp = (float4*)(h1 + (size_t)n * F_HID);
    hp[0] = make_float4(acc[0], acc[1], acc[2], acc[3]);
    hp[1] = make_float4(acc[4], acc[5], acc[6], acc[7]);
    as1[n] = s;
    ad1[n] = d;
}

// ---------- fused layer 1: one block per bucket (128 nodes), own padded range only ----------
// LDS counting sort (int atomics), emits padded e_srcP + rowinfo, then 4-lane-team
// aggregation from LDS. Max-free softmax (scores bounded; exp safe in fp32).
// Epilogue packs P2[node] = (as2, h2x, h2y, ad2) for gat2's single-gather loop.
__global__ void gatF1_k(const int* __restrict__ gcnt, const int* __restrict__ partP,
                        int* __restrict__ e_srcP, int2* __restrict__ rowinfo,
                        const float* __restrict__ as1, const float* __restrict__ ad1,
                        const float* __restrict__ h1, const float* __restrict__ b1,
                        const float* __restrict__ W2, const float* __restrict__ aw_s2,
                        const float* __restrict__ aw_d2, float4* __restrict__ P2) {
    __shared__ int eL[CAP];
    __shared__ int hist[GNPB];
    __shared__ int nstart[GNPB];
    __shared__ int cursor[GNPB];
    __shared__ int sscan[GNPB];
    __shared__ float adl[GNPB];
    int t = threadIdx.x;
    int c = blockIdx.x;
    int nbase = c << GSHIFT;
    int beg = c * CAP;
    int cnt = gcnt[c]; if (cnt > CAP) cnt = CAP;

    if (t < GNPB) {
        hist[t] = 0;
        adl[t] = (nbase + t < N_NODES) ? ad1[nbase + t] : 0.f;
    }
    __syncthreads();
    // histogram of local dst
    for (int j = t; j < cnt; j += BPG)
        atomicAdd(&hist[partP[beg + j] & (GNPB - 1)], 1);
    __syncthreads();
    if (t < GNPB) sscan[t] = hist[t];
    __syncthreads();
    for (int o = 1; o < GNPB; o <<= 1) {
        int u = (t < GNPB && t >= o) ? sscan[t - o] : 0;
        __syncthreads();
        if (t < GNPB) sscan[t] += u;
        __syncthreads();
    }
    if (t < GNPB) {
        int ex = sscan[t] - hist[t];
        nstart[t] = ex;
        cursor[t] = ex;
        int node = nbase + t;
        if (node < N_NODES) rowinfo[node] = make_int2(beg + ex, hist[t]);
    }
    __syncthreads();
    // scatter src into LDS sorted by local dst
    for (int j = t; j < cnt; j += BPG) {
        int pk = partP[beg + j];
        int pos = atomicAdd(&cursor[pk & (GNPB - 1)], 1);
        eL[pos] = pk >> GSHIFT;
    }
    __syncthreads();
    // write sorted e_srcP for gat2 (coalesced, padded layout)
    for (int i = t; i < cnt; i += BPG) e_srcP[beg + i] = eL[i];

    // aggregate: 4-lane team per node (512/4 = 128 teams)
    int node = t >> 2;
    int lane = t & 3;
    int gnode = nbase + node;
    if (gnode >= N_NODES) return;
    int ns = nstart[node];
    int ne = ns + hist[node];
    float add = adl[node];

    float denom = 0.f;
    float acc[F_HID];
#pragma unroll
    for (int f = 0; f < F_HID; f++) acc[f] = 0.f;
    for (int i = ns + lane; i < ne; i += 4) {
        int s = eL[i];
        float e = as1[s] + add;
        e = e >= 0.f ? e : NEG_SLOPE * e;
        float ee = __expf(e);
        denom += ee;
        const float4* hp = (const float4*)(h1 + (size_t)s * F_HID);
        float4 p0 = hp[0], p1 = hp[1];
        acc[0] += ee * p0.x; acc[1] += ee * p0.y; acc[2] += ee * p0.z; acc[3] += ee * p0.w;
        acc[4] += ee * p1.x; acc[5] += ee * p1.y; acc[6] += ee * p1.z; acc[7] += ee * p1.w;
    }
#pragma unroll
    for (int o = 2; o > 0; o >>= 1) {
        denom += __shfl_xor(denom, o, 4);
#pragma unroll
        for (int f = 0; f < F_HID; f++) acc[f] += __shfl_xor(acc[f], o, 4);
    }
    if (lane == 0) {
        float inv = denom > 0.f ? 1.f / denom : 0.f;
        float o0 = 0.f, o1 = 0.f;
#pragma unroll
        for (int f = 0; f < F_HID; f++) {
            float v = acc[f] * inv + b1[f];
            v = v > 0.f ? v : 0.f;  // relu
            o0 += v * W2[f * F_OUT + 0];
            o1 += v * W2[f * F_OUT + 1];
        }
        float as2v = o0 * aw_s2[0] + o1 * aw_s2[1];
        float ad2v = o0 * aw_d2[0] + o1 * aw_d2[1];
        P2[gnode] = make_float4(as2v, o0, o1, ad2v);
    }
}

// ---------- fused layer 2: 16 lanes/node, single float4 gather per edge ----------
__global__ void gat2_k(const int2* __restrict__ rowinfo, const int* __restrict__ e_srcP,
                       const float4* __restrict__ P2, const float* __restrict__ b2,
                       float* __restrict__ out, int n_nodes) {
    int gid = blockIdx.x * 16 + (threadIdx.x >> 4);
    int lane = threadIdx.x & 15;
    if (gid >= n_nodes) return;
    int2 ri = rowinfo[gid];
    float add = P2[gid].w;  // ad2 of dst node

    float denom = 0.f, a0 = 0.f, a1 = 0.f;
    int jend = ri.x + ri.y;
    for (int j = ri.x + lane; j < jend; j += 16) {
        int s = e_srcP[j];
        float4 q = P2[s];   // (as2, h2x, h2y, ad2)
        float e = q.x + add;
        e = e >= 0.f ? e : NEG_SLOPE * e;
        float ee = __expf(e);
        denom += ee;
        a0 += ee * q.y;
        a1 += ee * q.z;
    }
#pragma unroll
    for (int o = 8; o > 0; o >>= 1) {
        denom += __shfl_xor(denom, o, 16);
        a0 += __shfl_xor(a0, o, 16);
        a1 += __shfl_xor(a1, o, 16);
    }

    if (lane == 0) {
        float inv = denom > 0.f ? 1.f / denom : 0.f;
        float o0 = a0 * inv + b2[0];
        float o1 = a1 * inv + b2[1];
        float M = fmaxf(o0, o1);
        float l = M + logf(__expf(o0 - M) + __expf(o1 - M));
        ((float2*)out)[gid] = make_float2(o0 - l, o1 - l);
    }
}

extern "C" void kernel_launch(void* const* d_in, const int* in_sizes, int n_in,
                              void* d_out, int out_size, void* d_ws, size_t ws_size,
                              hipStream_t stream) {
    const float* x      = (const float*)d_in[0];
    const void*  eidx   = d_in[1];
    const float* W1     = (const float*)d_in[2];
    const float* a_src1 = (const float*)d_in[3];
    const float* a_dst1 = (const float*)d_in[4];
    const float* b1     = (const float*)d_in[5];
    const float* W2     = (const float*)d_in[6];
    const float* a_src2 = (const float*)d_in[7];
    const float* a_dst2 = (const float*)d_in[8];
    const float* b2     = (const float*)d_in[9];
    float* out = (float*)d_out;

    const size_t N = N_NODES;
    const size_t PADDED = (size_t)GNBUCK * CAP;   // 3,603,456

    // ---- workspace layout (4B words; offsets all stay multiples of 4) ----
    int* wsi = (int*)d_ws;
    float* wsf = (float*)d_ws;
    size_t o = 0;
    int* partP    = wsi + o;      o += PADDED;     // packed (src<<7)|(dst&127), padded buckets
    int* e_srcP   = wsi + o;      o += PADDED;     // dst-sorted src, padded buckets
    int* gcnt     = wsi + o;      o += 800;        // 782 bucket counts (zeroed)
    int2* rowinfo = (int2*)(wsi + o); o += 2 * N;  // (start, len) per node, 8B aligned
    float* as1    = wsf + o;      o += N;
    float* ad1    = wsf + o;      o += N;
    float* h1     = wsf + o;      o += 8 * N;      // 16B aligned
    float4* P2    = (float4*)(wsf + o); o += 4 * N; // (as2, h2x, h2y, ad2), 16B aligned

    const int B = 256;
    const int gridN = (int)((N + B - 1) / B);   // 391
    const int gridG = (int)(N / 16);            // 6250

    hipMemsetAsync(gcnt, 0, 800 * sizeof(int), stream);

    partition1_k<<<NB_PART, BP, 0, stream>>>(eidx, gcnt, partP);
    node1_k<<<gridN, B, 0, stream>>>(x, W1, a_src1, a_dst1, h1, as1, ad1, (int)N);
    gatF1_k<<<GNBUCK, BPG, 0, stream>>>(gcnt, partP, e_srcP, rowinfo, as1, ad1, h1, b1,
                                        W2, a_src2, a_dst2, P2);
    gat2_k<<<gridG, B, 0, stream>>>(rowinfo, e_srcP, P2, b2, out, (int)N);
}